// Round 2
// baseline (2620.391 us; speedup 1.0000x reference)
//
#include <hip/hip_runtime.h>

#define THREADS 256
#define RB 12                 // output rows per block (5 bands x 12 = 60 exact)
#define IN_ROWS 16            // RB + 4 halo rows staged
#define PS 64                 // floats per LDS row (no pad needed: reads are lane-consecutive b32)
#define LDS_FLOATS (6 * IN_ROWS * PS)   // 6144 floats = 24576 B

// inverse connectivity: for each input channel, the 10 output maps it feeds
__device__ constexpr int CONN_INV[6][10] = {
    {0, 4, 5, 6, 9, 10, 11, 12, 14, 15},
    {0, 1, 5, 6, 7, 10, 11, 12, 13, 15},
    {0, 1, 2, 6, 7, 8, 11, 13, 14, 15},
    {1, 2, 3, 6, 7, 8, 9, 12, 14, 15},
    {2, 3, 4, 7, 8, 9, 10, 12, 13, 15},
    {3, 4, 5, 8, 9, 10, 11, 13, 14, 15},
};

__global__ __launch_bounds__(THREADS, 6)   // 6 waves/EU -> 24 waves/CU target
void c3_conv(const float* __restrict__ x, const float* __restrict__ W,
             const float* __restrict__ bias, float* __restrict__ out) {
    // +4 floats pad: lanes 60-63 read up to 3 floats past the last row (values unused)
    __shared__ float xs[LDS_FLOATS + 4];

    const int blk  = blockIdx.x;
    const int img  = blk / 5;
    const int band = blk - img * 5;
    const int r0   = band * RB;
    const int t    = threadIdx.x;

    // ---- stage input tile: 6 ch x 16 rows x 64 cols, f32, float4 loads ----
    // LDS layout [ic][iy][col] contiguous == linear in s.
    {
        const float4* src = reinterpret_cast<const float4*>(x) + (size_t)img * 6144;
        float4* dst = reinterpret_cast<float4*>(xs);
        #pragma unroll
        for (int k = 0; k < 6; ++k) {
            int s  = t + k * THREADS;        // 0..1535
            int ic = s >> 8;                 // 256 float4 per channel tile
            int iy = (s >> 4) & 15;
            int c4 = s & 15;
            dst[s] = src[ic * 1024 + (r0 + iy) * 16 + c4];
        }
    }
    __syncthreads();

    const int w    = t >> 6;                 // wave 0..3
    const int lane = t & 63;                 // lane = output column (0..59 valid)

    #pragma unroll 1
    for (int k = 0; k < 3; ++k) {
        const int lr = w + 4 * k;            // local output row 0..11, interleaved by wave
        const int y  = r0 + lr;

        float acc[16];
        #pragma unroll
        for (int oc = 0; oc < 16; ++oc) acc[oc] = bias[oc];   // uniform -> s_load

        // single vaddr: lr*PS + lane; all (ic,ky,kx) offsets are compile-time
        // immediates (max (5*16+4)*64*4 + 16 = 21520 B, fits 16-bit DS offset)
        const float* base = xs + lr * PS + lane;

        #pragma unroll
        for (int ic = 0; ic < 6; ++ic) {
            #pragma unroll
            for (int ky = 0; ky < 5; ++ky) {
                const float* p = base + (ic * IN_ROWS + ky) * PS;
                float xv0 = p[0];
                float xv1 = p[1];
                float xv2 = p[2];
                float xv3 = p[3];
                float xv4 = p[4];
                #pragma unroll
                for (int u = 0; u < 10; ++u) {
                    const int oc = CONN_INV[ic][u];
                    const float* wp = W + ((oc * 6 + ic) * 5 + ky) * 5;  // uniform -> s_load
                    acc[oc] = fmaf(xv0, wp[0], acc[oc]);
                    acc[oc] = fmaf(xv1, wp[1], acc[oc]);
                    acc[oc] = fmaf(xv2, wp[2], acc[oc]);
                    acc[oc] = fmaf(xv3, wp[3], acc[oc]);
                    acc[oc] = fmaf(xv4, wp[4], acc[oc]);
                }
            }
        }

        if (lane < 60) {
            float* op = out + (size_t)img * 57600 + (size_t)y * 60 + lane;
            #pragma unroll
            for (int oc = 0; oc < 16; ++oc) op[oc * 3600] = acc[oc];
        }
    }
}

extern "C" void kernel_launch(void* const* d_in, const int* in_sizes, int n_in,
                              void* d_out, int out_size, void* d_ws, size_t ws_size,
                              hipStream_t stream) {
    const float* x  = (const float*)d_in[0];
    const float* W  = (const float*)d_in[1];
    const float* b  = (const float*)d_in[2];
    float* out      = (float*)d_out;

    const int nimg = in_sizes[0] / (6 * 64 * 64);   // 2048
    dim3 grid(nimg * 5), block(THREADS);
    hipLaunchKernelGGL(c3_conv, grid, block, 0, stream, x, W, b, out);
}

// Round 3
// 2291.344 us; speedup vs baseline: 1.1436x; 1.1436x over previous
//
#include <hip/hip_runtime.h>

#define THREADS 384           // 6 waves; each wave owns 2 output rows
#define RB 12                 // output rows per block (5 bands x 12 = 60 exact)
#define IN_ROWS 16            // RB + 4 halo rows staged
#define PS 64                 // floats per staged LDS row
#define LDS_FLOATS (6 * IN_ROWS * PS)   // 6144 floats = 24576 B

// ---- named-scalar accumulator machinery (NO arrays -> nothing can spill) ----
#define DECL(OC) float A0_##OC = bias[OC], A1_##OC = bias[OC]

// 5-tap FMA into accumulator A{T}_{OC}; all of OC, IC, KY are literals, so
// wp_ is a uniform compile-time offset from W -> s_load on the scalar pipe.
#define UPD(T, OC, IC, KY) do { \
    const float* wp_ = W + ((OC * 6 + IC) * 5 + KY) * 5; \
    A##T##_##OC = fmaf(xv0, wp_[0], A##T##_##OC); \
    A##T##_##OC = fmaf(xv1, wp_[1], A##T##_##OC); \
    A##T##_##OC = fmaf(xv2, wp_[2], A##T##_##OC); \
    A##T##_##OC = fmaf(xv3, wp_[3], A##T##_##OC); \
    A##T##_##OC = fmaf(xv4, wp_[4], A##T##_##OC); \
} while (0)

// per input channel: the 10 connected output maps (LeNet C3 table, inverted)
#define UPD_IC0(T, KY) UPD(T,0,0,KY);  UPD(T,4,0,KY);  UPD(T,5,0,KY);  UPD(T,6,0,KY);  UPD(T,9,0,KY);  UPD(T,10,0,KY); UPD(T,11,0,KY); UPD(T,12,0,KY); UPD(T,14,0,KY); UPD(T,15,0,KY)
#define UPD_IC1(T, KY) UPD(T,0,1,KY);  UPD(T,1,1,KY);  UPD(T,5,1,KY);  UPD(T,6,1,KY);  UPD(T,7,1,KY);  UPD(T,10,1,KY); UPD(T,11,1,KY); UPD(T,12,1,KY); UPD(T,13,1,KY); UPD(T,15,1,KY)
#define UPD_IC2(T, KY) UPD(T,0,2,KY);  UPD(T,1,2,KY);  UPD(T,2,2,KY);  UPD(T,6,2,KY);  UPD(T,7,2,KY);  UPD(T,8,2,KY);  UPD(T,11,2,KY); UPD(T,13,2,KY); UPD(T,14,2,KY); UPD(T,15,2,KY)
#define UPD_IC3(T, KY) UPD(T,1,3,KY);  UPD(T,2,3,KY);  UPD(T,3,3,KY);  UPD(T,6,3,KY);  UPD(T,7,3,KY);  UPD(T,8,3,KY);  UPD(T,9,3,KY);  UPD(T,12,3,KY); UPD(T,14,3,KY); UPD(T,15,3,KY)
#define UPD_IC4(T, KY) UPD(T,2,4,KY);  UPD(T,3,4,KY);  UPD(T,4,4,KY);  UPD(T,7,4,KY);  UPD(T,8,4,KY);  UPD(T,9,4,KY);  UPD(T,10,4,KY); UPD(T,12,4,KY); UPD(T,13,4,KY); UPD(T,15,4,KY)
#define UPD_IC5(T, KY) UPD(T,3,5,KY);  UPD(T,4,5,KY);  UPD(T,5,5,KY);  UPD(T,8,5,KY);  UPD(T,9,5,KY);  UPD(T,10,5,KY); UPD(T,11,5,KY); UPD(T,13,5,KY); UPD(T,14,5,KY); UPD(T,15,5,KY)

// load one staged input row into xv0..4 (one vaddr + DS immediate offsets)
#define LOADROW(IC, IY) do { \
    const float* p_ = base + (IC * IN_ROWS + IY) * PS; \
    xv0 = p_[0]; xv1 = p_[1]; xv2 = p_[2]; xv3 = p_[3]; xv4 = p_[4]; \
} while (0)

// one input channel: 6 input rows feed 2 output rows (t=0: ky=iy; t=1: ky=iy-1)
#define CHAN(IC) \
    LOADROW(IC,0); UPD_IC##IC(0,0); \
    LOADROW(IC,1); UPD_IC##IC(0,1); UPD_IC##IC(1,0); \
    LOADROW(IC,2); UPD_IC##IC(0,2); UPD_IC##IC(1,1); \
    LOADROW(IC,3); UPD_IC##IC(0,3); UPD_IC##IC(1,2); \
    LOADROW(IC,4); UPD_IC##IC(0,4); UPD_IC##IC(1,3); \
    LOADROW(IC,5);                  UPD_IC##IC(1,4)

#define ST(T, OC) op[(OC) * 3600 + (T) * 60] = A##T##_##OC

__global__ __launch_bounds__(THREADS, 4)
void c3_conv(const float* __restrict__ x, const float* __restrict__ W,
             const float* __restrict__ bias, float* __restrict__ out) {
    // +4 pad: xv reads of the very last staged row touch up to 3 floats past it
    __shared__ float xs[LDS_FLOATS + 4];

    const int blk  = blockIdx.x;
    const int img  = blk / 5;
    const int band = blk - img * 5;
    const int r0   = band * RB;
    const int t    = threadIdx.x;

    // ---- stage input tile: 6 ch x 16 rows x 64 cols, f32, float4 loads ----
    {
        const float4* src = reinterpret_cast<const float4*>(x) + (size_t)img * 6144;
        float4* dst = reinterpret_cast<float4*>(xs);
        #pragma unroll
        for (int k = 0; k < 4; ++k) {
            int s  = t + k * THREADS;        // 0..1535
            int ic = s >> 8;                 // 256 float4 per channel tile
            int iy = (s >> 4) & 15;
            int c4 = s & 15;
            dst[s] = src[ic * 1024 + (r0 + iy) * 16 + c4];
        }
    }
    __syncthreads();

    const int w    = t >> 6;                 // wave 0..5
    const int lr0  = 2 * w;                  // this wave's first output row (local)
    const int lane = t & 63;                 // lane = output column (0..59 valid)

    DECL(0);  DECL(1);  DECL(2);  DECL(3);  DECL(4);  DECL(5);  DECL(6);  DECL(7);
    DECL(8);  DECL(9);  DECL(10); DECL(11); DECL(12); DECL(13); DECL(14); DECL(15);

    float xv0, xv1, xv2, xv3, xv4;
    const float* base = xs + lr0 * PS + lane;   // single vaddr; all else immediates

    CHAN(0); CHAN(1); CHAN(2); CHAN(3); CHAN(4); CHAN(5);

    if (lane < 60) {
        float* op = out + (size_t)img * 57600 + (size_t)(r0 + lr0) * 60 + lane;
        ST(0,0);  ST(0,1);  ST(0,2);  ST(0,3);  ST(0,4);  ST(0,5);  ST(0,6);  ST(0,7);
        ST(0,8);  ST(0,9);  ST(0,10); ST(0,11); ST(0,12); ST(0,13); ST(0,14); ST(0,15);
        ST(1,0);  ST(1,1);  ST(1,2);  ST(1,3);  ST(1,4);  ST(1,5);  ST(1,6);  ST(1,7);
        ST(1,8);  ST(1,9);  ST(1,10); ST(1,11); ST(1,12); ST(1,13); ST(1,14); ST(1,15);
    }
}

extern "C" void kernel_launch(void* const* d_in, const int* in_sizes, int n_in,
                              void* d_out, int out_size, void* d_ws, size_t ws_size,
                              hipStream_t stream) {
    const float* x  = (const float*)d_in[0];
    const float* W  = (const float*)d_in[1];
    const float* b  = (const float*)d_in[2];
    float* out      = (float*)d_out;

    const int nimg = in_sizes[0] / (6 * 64 * 64);   // 2048
    dim3 grid(nimg * 5), block(THREADS);
    hipLaunchKernelGGL(c3_conv, grid, block, 0, stream, x, W, b, out);
}

// Round 4
// 329.700 us; speedup vs baseline: 7.9478x; 6.9498x over previous
//
#include <hip/hip_runtime.h>

#define THREADS 384           // 6 waves; each wave owns 2 output rows
#define RB 12                 // output rows per block (5 bands x 12 = 60 exact)
#define IN_ROWS 16            // RB + 4 halo rows staged
#define PS 64                 // floats per staged LDS row
#define LDS_FLOATS (6 * IN_ROWS * PS)   // 6144 floats = 24576 B

// ---- named-scalar accumulators: NOTHING indexable, nothing can spill ----
#define DECL(OC) float A0_##OC = bias[OC], A1_##OC = bias[OC]

// load this ky's two input rows (T0: row lr0+ky, T1: row lr0+ky+1) for channel IC
// one vaddr (brow) + compile-time DS immediates; lane-consecutive -> conflict-free
#define LOADX(IC) do { \
    const float* p_ = brow + (IC) * (IN_ROWS * PS); \
    xa0 = p_[0];      xa1 = p_[1];      xa2 = p_[2];      xa3 = p_[3];      xa4 = p_[4]; \
    xb0 = p_[PS + 0]; xb1 = p_[PS + 1]; xb2 = p_[PS + 2]; xb3 = p_[PS + 3]; xb4 = p_[PS + 4]; \
} while (0)

// one (oc,ic) 5-tap group at the loop's ky: load 5 weights once (uniform ->
// scalar pipe), use each for BOTH output rows (reuse x2)
#define UPD2(OC, IC) do { \
    const float* wp_ = Wky + (OC) * 150 + (IC) * 25; \
    const float w0_ = wp_[0], w1_ = wp_[1], w2_ = wp_[2], w3_ = wp_[3], w4_ = wp_[4]; \
    A0_##OC = fmaf(xa0, w0_, A0_##OC);  A1_##OC = fmaf(xb0, w0_, A1_##OC); \
    A0_##OC = fmaf(xa1, w1_, A0_##OC);  A1_##OC = fmaf(xb1, w1_, A1_##OC); \
    A0_##OC = fmaf(xa2, w2_, A0_##OC);  A1_##OC = fmaf(xb2, w2_, A1_##OC); \
    A0_##OC = fmaf(xa3, w3_, A0_##OC);  A1_##OC = fmaf(xb3, w3_, A1_##OC); \
    A0_##OC = fmaf(xa4, w4_, A0_##OC);  A1_##OC = fmaf(xb4, w4_, A1_##OC); \
} while (0)

#define SBAR __builtin_amdgcn_sched_barrier(0)

// per input channel: its 10 connected output maps; sched_barrier caps the
// scheduler's hoisting window at ~50 weights + 10 x values (no pressure blowup)
#define CHAN0 LOADX(0); UPD2(0,0);  UPD2(4,0);  UPD2(5,0);  UPD2(6,0);  UPD2(9,0);  UPD2(10,0); UPD2(11,0); UPD2(12,0); UPD2(14,0); UPD2(15,0); SBAR
#define CHAN1 LOADX(1); UPD2(0,1);  UPD2(1,1);  UPD2(5,1);  UPD2(6,1);  UPD2(7,1);  UPD2(10,1); UPD2(11,1); UPD2(12,1); UPD2(13,1); UPD2(15,1); SBAR
#define CHAN2 LOADX(2); UPD2(0,2);  UPD2(1,2);  UPD2(2,2);  UPD2(6,2);  UPD2(7,2);  UPD2(8,2);  UPD2(11,2); UPD2(13,2); UPD2(14,2); UPD2(15,2); SBAR
#define CHAN3 LOADX(3); UPD2(1,3);  UPD2(2,3);  UPD2(3,3);  UPD2(6,3);  UPD2(7,3);  UPD2(8,3);  UPD2(9,3);  UPD2(12,3); UPD2(14,3); UPD2(15,3); SBAR
#define CHAN4 LOADX(4); UPD2(2,4);  UPD2(3,4);  UPD2(4,4);  UPD2(7,4);  UPD2(8,4);  UPD2(9,4);  UPD2(10,4); UPD2(12,4); UPD2(13,4); UPD2(15,4); SBAR
#define CHAN5 LOADX(5); UPD2(3,5);  UPD2(4,5);  UPD2(5,5);  UPD2(8,5);  UPD2(9,5);  UPD2(10,5); UPD2(11,5); UPD2(13,5); UPD2(14,5); UPD2(15,5); SBAR

#define ST(T, OC) op[(OC) * 3600 + (T) * 60] = A##T##_##OC

__global__ __launch_bounds__(THREADS, 4)
void c3_conv(const float* __restrict__ x, const float* __restrict__ W,
             const float* __restrict__ bias, float* __restrict__ out) {
    // +4 floats pad: lane 63 reads up to col 67 of the last staged row (unused vals)
    __shared__ float xs[LDS_FLOATS + 4];

    const int blk  = blockIdx.x;
    const int img  = blk / 5;
    const int band = blk - img * 5;
    const int r0   = band * RB;
    const int t    = threadIdx.x;

    // ---- stage input tile: 6 ch x 16 rows x 64 cols, f32, float4 loads ----
    {
        const float4* src = reinterpret_cast<const float4*>(x) + (size_t)img * 6144;
        float4* dst = reinterpret_cast<float4*>(xs);
        #pragma unroll
        for (int k = 0; k < 4; ++k) {
            int s  = t + k * THREADS;        // 0..1535
            int ic = s >> 8;                 // 256 float4 per channel tile
            int iy = (s >> 4) & 15;
            int c4 = s & 15;
            dst[s] = src[ic * 1024 + (r0 + iy) * 16 + c4];
        }
    }
    __syncthreads();

    const int w    = t >> 6;                 // wave 0..5
    const int lr0  = 2 * w;                  // this wave's first output row (local)
    const int lane = t & 63;                 // lane = output column (0..59 valid)

    DECL(0);  DECL(1);  DECL(2);  DECL(3);  DECL(4);  DECL(5);  DECL(6);  DECL(7);
    DECL(8);  DECL(9);  DECL(10); DECL(11); DECL(12); DECL(13); DECL(14); DECL(15);

    float xa0, xa1, xa2, xa3, xa4;           // T0's input row for current ky
    float xb0, xb1, xb2, xb3, xb4;           // T1's input row for current ky

    // runtime ky loop: bounds the scheduler window, keeps body ~5 KB (fits I$)
    #pragma unroll 1
    for (int ky = 0; ky < 5; ++ky) {
        const float* brow = xs + (lr0 + ky) * PS + lane;  // single vaddr per iter
        const float* Wky  = W + ky * 5;                   // uniform SGPR base
        CHAN0; CHAN1; CHAN2; CHAN3; CHAN4; CHAN5;
    }

    if (lane < 60) {
        float* op = out + (size_t)img * 57600 + (size_t)(r0 + lr0) * 60 + lane;
        ST(0,0);  ST(0,1);  ST(0,2);  ST(0,3);  ST(0,4);  ST(0,5);  ST(0,6);  ST(0,7);
        ST(0,8);  ST(0,9);  ST(0,10); ST(0,11); ST(0,12); ST(0,13); ST(0,14); ST(0,15);
        ST(1,0);  ST(1,1);  ST(1,2);  ST(1,3);  ST(1,4);  ST(1,5);  ST(1,6);  ST(1,7);
        ST(1,8);  ST(1,9);  ST(1,10); ST(1,11); ST(1,12); ST(1,13); ST(1,14); ST(1,15);
    }
}

extern "C" void kernel_launch(void* const* d_in, const int* in_sizes, int n_in,
                              void* d_out, int out_size, void* d_ws, size_t ws_size,
                              hipStream_t stream) {
    const float* x  = (const float*)d_in[0];
    const float* W  = (const float*)d_in[1];
    const float* b  = (const float*)d_in[2];
    float* out      = (float*)d_out;

    const int nimg = in_sizes[0] / (6 * 64 * 64);   // 2048
    dim3 grid(nimg * 5), block(THREADS);
    hipLaunchKernelGGL(c3_conv, grid, block, 0, stream, x, W, b, out);
}